// Round 2
// baseline (322.600 us; speedup 1.0000x reference)
//
#include <hip/hip_runtime.h>

// Problem constants (fixed by the reference)
#define B_N   8
#define S_N   2048
#define K_N   21
#define L_N   16
#define CM_N  256
#define SCHUNK 128
#define CHUNKS (S_N / SCHUNK)   // 16

__global__ __launch_bounds__(256) void pssm_proj_kernel(
    const float* __restrict__ x,     // [B,S,K]
    const float* __restrict__ W,     // [L,CM,K]
    const float* __restrict__ bias,  // [L,CM]
    float* __restrict__ out)         // [B,L,S,CM]
{
    // x rows staged in LDS, padded to 24 floats so each row is float4-aligned
    __shared__ float xs[SCHUNK][24];

    const int tid   = threadIdx.x;
    const int bx    = blockIdx.x;
    const int chunk = bx % CHUNKS;
    const int l     = (bx / CHUNKS) % L_N;
    const int b     = bx / (CHUNKS * L_N);
    const int s0    = chunk * SCHUNK;

    // ---- stage x[b, s0:s0+SCHUNK, 0:21] -> LDS (coalesced fp32 loads) ----
    const float* xbase = x + ((size_t)b * S_N + s0) * K_N;
    for (int idx = tid; idx < SCHUNK * K_N; idx += 256) {
        int r = idx / K_N;
        int k = idx - r * K_N;
        xs[r][k] = xbase[idx];
    }

    // ---- per-lane W fragment: 4 consecutive c per lane (wave covers 256 c) ----
    const int lane = tid & 63;
    const int wave = tid >> 6;
    const int c0   = lane * 4;
    float wf[4][K_N];
    float bv[4];
#pragma unroll
    for (int j = 0; j < 4; ++j) {
        const float* wrow = W + ((size_t)l * CM_N + (c0 + j)) * K_N;
#pragma unroll
        for (int k = 0; k < K_N; ++k)
            wf[j][k] = wrow[k];
        bv[j] = bias[l * CM_N + c0 + j];
    }

    __syncthreads();

    float* outbase = out + (((size_t)b * L_N + l) * S_N + s0) * CM_N + c0;

    // each wave sweeps rows {wave, wave+4, ...}: 32 rows/wave
    for (int i = 0; i < SCHUNK / 4; ++i) {
        const int r = i * 4 + wave;
        const float4* xv = (const float4*)(&xs[r][0]);  // wave-uniform broadcast reads

        float a0 = bv[0], a1 = bv[1], a2 = bv[2], a3 = bv[3];
#pragma unroll
        for (int kb = 0; kb < 6; ++kb) {
            float4 xq = xv[kb];
            float xe[4] = {xq.x, xq.y, xq.z, xq.w};
#pragma unroll
            for (int e = 0; e < 4; ++e) {
                const int k = kb * 4 + e;
                if (k < K_N) {   // compile-time guard (K=21 < 24 pad; tail unused)
                    a0 += xe[e] * wf[0][k];
                    a1 += xe[e] * wf[1][k];
                    a2 += xe[e] * wf[2][k];
                    a3 += xe[e] * wf[3][k];
                }
            }
        }

        float4 o = make_float4(a0, a1, a2, a3);
        *(float4*)(outbase + (size_t)r * CM_N) = o;   // 16 B/lane, 1 KiB/wave contiguous
    }
}

extern "C" void kernel_launch(void* const* d_in, const int* in_sizes, int n_in,
                              void* d_out, int out_size, void* d_ws, size_t ws_size,
                              hipStream_t stream) {
    const float* x    = (const float*)d_in[0];
    const float* W    = (const float*)d_in[1];
    const float* bias = (const float*)d_in[2];
    float* out        = (float*)d_out;

    dim3 grid(B_N * L_N * CHUNKS);   // 8*16*16 = 2048 blocks
    dim3 block(256);
    pssm_proj_kernel<<<grid, block, 0, stream>>>(x, W, bias, out);
}

// Round 4
// 280.973 us; speedup vs baseline: 1.1482x; 1.1482x over previous
//
#include <hip/hip_runtime.h>

// Problem constants (fixed by the reference)
#define B_N   8
#define S_N   2048
#define K_N   21
#define L_N   16
#define CM_N  256
#define SCHUNK 128
#define CHUNKS (S_N / SCHUNK)   // 16

// native clang vector type — accepted by __builtin_nontemporal_store
typedef float vfloat4 __attribute__((ext_vector_type(4)));

__global__ __launch_bounds__(256, 4) void pssm_proj_kernel(
    const float* __restrict__ x,     // [B,S,K]
    const float* __restrict__ W,     // [L,CM,K]
    const float* __restrict__ bias,  // [L,CM]
    float* __restrict__ out)         // [B,L,S,CM]
{
    // x rows staged in LDS, padded to 24 floats so each row is float4-aligned
    __shared__ float xs[SCHUNK][24];

    const int tid   = threadIdx.x;
    const int bx    = blockIdx.x;
    const int chunk = bx % CHUNKS;
    const int l     = (bx / CHUNKS) % L_N;
    const int b     = bx / (CHUNKS * L_N);
    const int s0    = chunk * SCHUNK;

    // ---- stage x[b, s0:s0+SCHUNK, 0:21] -> LDS (coalesced fp32 loads) ----
    const float* xbase = x + ((size_t)b * S_N + s0) * K_N;
    for (int idx = tid; idx < SCHUNK * K_N; idx += 256) {
        int r = idx / K_N;
        int k = idx - r * K_N;
        xs[r][k] = xbase[idx];
    }

    // ---- per-lane W fragment: 4 consecutive c per lane (wave covers 256 c) ----
    const int lane = tid & 63;
    const int wave = tid >> 6;
    const int c0   = lane * 4;
    float wf[4][K_N];
    float bv[4];
#pragma unroll
    for (int j = 0; j < 4; ++j) {
        const float* wrow = W + ((size_t)l * CM_N + (c0 + j)) * K_N;
#pragma unroll
        for (int k = 0; k < K_N; ++k)
            wf[j][k] = wrow[k];
        bv[j] = bias[l * CM_N + c0 + j];
    }

    __syncthreads();

    float* outbase = out + (((size_t)b * L_N + l) * S_N + s0) * CM_N + c0;

    // each wave sweeps rows {wave, wave+4, ...}: 32 rows/wave
    for (int i = 0; i < SCHUNK / 4; ++i) {
        const int r = i * 4 + wave;
        const vfloat4* xv = (const vfloat4*)(&xs[r][0]);  // wave-uniform broadcast reads

        float a0 = bv[0], a1 = bv[1], a2 = bv[2], a3 = bv[3];
#pragma unroll
        for (int kb = 0; kb < 6; ++kb) {
            vfloat4 xq = xv[kb];
            float xe[4] = {xq.x, xq.y, xq.z, xq.w};
#pragma unroll
            for (int e = 0; e < 4; ++e) {
                const int k = kb * 4 + e;
                if (k < K_N) {   // compile-time guard (K=21 < 24 pad; tail unused)
                    a0 += xe[e] * wf[0][k];
                    a1 += xe[e] * wf[1][k];
                    a2 += xe[e] * wf[2][k];
                    a3 += xe[e] * wf[3][k];
                }
            }
        }

        // nontemporal: output has zero reuse — don't allocate 256 MiB through 32 MiB L2
        vfloat4 o = {a0, a1, a2, a3};
        __builtin_nontemporal_store(o, (vfloat4*)(outbase + (size_t)r * CM_N));
    }
}

extern "C" void kernel_launch(void* const* d_in, const int* in_sizes, int n_in,
                              void* d_out, int out_size, void* d_ws, size_t ws_size,
                              hipStream_t stream) {
    const float* x    = (const float*)d_in[0];
    const float* W    = (const float*)d_in[1];
    const float* bias = (const float*)d_in[2];
    float* out        = (float*)d_out;

    dim3 grid(B_N * L_N * CHUNKS);   // 8*16*16 = 2048 blocks
    dim3 block(256);
    pssm_proj_kernel<<<grid, block, 0, stream>>>(x, W, bias, out);
}